// Round 1
// baseline (1289.193 us; speedup 1.0000x reference)
//
#include <hip/hip_runtime.h>
#include <cstdint>
#include <math.h>

#define SEQ 2048
#define BATCH 2
#define HID 1024
#define NH 16
#define HD 64
#define MROWS (SEQ * BATCH)  // 4096
#define ROWSTRIDE (BATCH * HID)  // 2048 floats between consecutive seq positions

// ---------------------------------------------------------------------------
// GEMM: C[m][n] = scale * (sum_k A[m][k] * W[n][k] + bias[n])
// A: [M][K] row-major, W: [N][K] row-major (i.e. x @ W^T like F.linear)
// 64x64 tile, BK=32, 256 threads, 4x4 accumulators per thread.
// ---------------------------------------------------------------------------
#define GBK 32
#define ALD 68  // padded leading dim for transposed LDS tiles (16B-aligned rows)

__global__ __launch_bounds__(256) void gemm_bt(const float* __restrict__ A,
                                               const float* __restrict__ W,
                                               const float* __restrict__ bias,
                                               float* __restrict__ C,
                                               int M, int N, int K, float scale) {
    __shared__ float As[GBK][ALD];  // As[k][m]
    __shared__ float Ws[GBK][ALD];  // Ws[k][n]
    const int t = threadIdx.x;
    const int tx = t & 15, ty = t >> 4;
    const int m0 = blockIdx.x * 64, n0 = blockIdx.y * 64;

    float acc[4][4] = {};

    for (int k0 = 0; k0 < K; k0 += GBK) {
        __syncthreads();
#pragma unroll
        for (int p = 0; p < 2; ++p) {
            int f = t + p * 256;        // 0..511 over 64 rows x 8 float4-chunks
            int m = f >> 3, kc = f & 7;
            float4 va = *(const float4*)&A[(size_t)(m0 + m) * K + k0 + kc * 4];
            As[kc * 4 + 0][m] = va.x; As[kc * 4 + 1][m] = va.y;
            As[kc * 4 + 2][m] = va.z; As[kc * 4 + 3][m] = va.w;
            float4 vw = *(const float4*)&W[(size_t)(n0 + m) * K + k0 + kc * 4];
            Ws[kc * 4 + 0][m] = vw.x; Ws[kc * 4 + 1][m] = vw.y;
            Ws[kc * 4 + 2][m] = vw.z; Ws[kc * 4 + 3][m] = vw.w;
        }
        __syncthreads();
#pragma unroll
        for (int k = 0; k < GBK; ++k) {
            float4 a4 = *(const float4*)&As[k][ty * 4];
            float4 b4 = *(const float4*)&Ws[k][tx * 4];
            float av[4] = {a4.x, a4.y, a4.z, a4.w};
            float bv[4] = {b4.x, b4.y, b4.z, b4.w};
#pragma unroll
            for (int i = 0; i < 4; ++i)
#pragma unroll
                for (int j = 0; j < 4; ++j)
                    acc[i][j] = fmaf(av[i], bv[j], acc[i][j]);
        }
    }

#pragma unroll
    for (int i = 0; i < 4; ++i) {
        int row = m0 + ty * 4 + i;
        int col = n0 + tx * 4;
        float4 o;
        o.x = scale * (acc[i][0] + bias[col + 0]);
        o.y = scale * (acc[i][1] + bias[col + 1]);
        o.z = scale * (acc[i][2] + bias[col + 2]);
        o.w = scale * (acc[i][3] + bias[col + 3]);
        *(float4*)&C[(size_t)row * N + col] = o;
    }
}

// ---------------------------------------------------------------------------
// Flash-style causal attention, fp32.
// Grid: (SEQ/64 q-tiles, BATCH*NH). Block: 256 threads (16x16), 4x4 per thread.
// Q pre-scaled by 1/sqrt(HD) at projection time.
// Layouts: Q/K/V/O are [seq][batch][heads*HD] fp32 (row = s*BATCH + b).
// O may alias Q: each block reads exactly the Q elements it later writes.
// ---------------------------------------------------------------------------
__global__ __launch_bounds__(256) void attn_fwd(const float* __restrict__ Q,
                                                const float* __restrict__ K,
                                                const float* __restrict__ V,
                                                float* __restrict__ O) {
    __shared__ float Qt[64 * 64];  // Qt[d][i] transposed
    __shared__ float Kt[64 * 64];  // Kt[d][j] transposed
    __shared__ float Vs[64 * 64];  // Vs[j][d] natural
    __shared__ float Ps[64 * 64];  // Ps[j][i] transposed

    const int t = threadIdx.x;
    const int tx = t & 15, ty = t >> 4;
    // heavy q-tiles first to mitigate causal imbalance
    const int qt = (int)gridDim.x - 1 - (int)blockIdx.x;
    const int bh = blockIdx.y;
    const int b = bh >> 4, h = bh & 15;
    const int q0 = qt * 64;
    const size_t headoff = (size_t)b * HID + (size_t)h * HD;

    // ---- load Q tile (transposed) ----
    const float* Qbase = Q + (size_t)q0 * ROWSTRIDE + headoff;
#pragma unroll
    for (int p = 0; p < 4; ++p) {
        int f = t + p * 256;          // 0..1023 over 64 rows x 16 chunks
        int i = f >> 4, dc = f & 15;
        float4 v = *(const float4*)&Qbase[(size_t)i * ROWSTRIDE + dc * 4];
        Qt[(dc * 4 + 0) * 64 + i] = v.x; Qt[(dc * 4 + 1) * 64 + i] = v.y;
        Qt[(dc * 4 + 2) * 64 + i] = v.z; Qt[(dc * 4 + 3) * 64 + i] = v.w;
    }

    float acc[4][4] = {};
    float mrow[4] = {-INFINITY, -INFINITY, -INFINITY, -INFINITY};
    float lrow[4] = {};

    for (int kt = 0; kt <= qt; ++kt) {
        const int k0 = kt * 64;
        __syncthreads();  // previous iteration done with Kt/Vs/Ps; Qt stores done
        const float* Kbase = K + (size_t)k0 * ROWSTRIDE + headoff;
        const float* Vbase = V + (size_t)k0 * ROWSTRIDE + headoff;
#pragma unroll
        for (int p = 0; p < 4; ++p) {
            int f = t + p * 256;
            int j = f >> 4, dc = f & 15;
            float4 v = *(const float4*)&Kbase[(size_t)j * ROWSTRIDE + dc * 4];
            Kt[(dc * 4 + 0) * 64 + j] = v.x; Kt[(dc * 4 + 1) * 64 + j] = v.y;
            Kt[(dc * 4 + 2) * 64 + j] = v.z; Kt[(dc * 4 + 3) * 64 + j] = v.w;
            float4 w = *(const float4*)&Vbase[(size_t)j * ROWSTRIDE + dc * 4];
            *(float4*)&Vs[j * 64 + dc * 4] = w;
        }
        __syncthreads();

        // ---- S = Q K^T (4x4 per thread) ----
        float s[4][4] = {};
#pragma unroll 8
        for (int d = 0; d < 64; ++d) {
            float4 a4 = *(const float4*)&Qt[d * 64 + ty * 4];
            float4 b4 = *(const float4*)&Kt[d * 64 + tx * 4];
            float av[4] = {a4.x, a4.y, a4.z, a4.w};
            float bv[4] = {b4.x, b4.y, b4.z, b4.w};
#pragma unroll
            for (int i = 0; i < 4; ++i)
#pragma unroll
                for (int j = 0; j < 4; ++j)
                    s[i][j] = fmaf(av[i], bv[j], s[i][j]);
        }

        // ---- causal mask on diagonal tile ----
        if (kt == qt) {
#pragma unroll
            for (int i = 0; i < 4; ++i)
#pragma unroll
                for (int j = 0; j < 4; ++j)
                    if (tx * 4 + j > ty * 4 + i) s[i][j] = -3.0e38f;
        }

        // ---- online softmax (rows shared across the 16-lane tx group) ----
        float pv[4][4];
#pragma unroll
        for (int a = 0; a < 4; ++a) {
            float rm = fmaxf(fmaxf(s[a][0], s[a][1]), fmaxf(s[a][2], s[a][3]));
#pragma unroll
            for (int o = 1; o < 16; o <<= 1) rm = fmaxf(rm, __shfl_xor(rm, o));
            float mn = fmaxf(mrow[a], rm);          // finite: every row has >=1 valid col
            float corr = __expf(mrow[a] - mn);      // first tile: exp(-inf) = 0
            float rl = 0.f;
#pragma unroll
            for (int j = 0; j < 4; ++j) {
                pv[a][j] = __expf(s[a][j] - mn);    // masked: exp(-3e38 - mn) -> 0
                rl += pv[a][j];
            }
#pragma unroll
            for (int o = 1; o < 16; o <<= 1) rl += __shfl_xor(rl, o);
            lrow[a] = lrow[a] * corr + rl;
            mrow[a] = mn;
#pragma unroll
            for (int j = 0; j < 4; ++j) acc[a][j] *= corr;
        }

        // ---- store P transposed: Ps[j][i] ----
#pragma unroll
        for (int a = 0; a < 4; ++a)
#pragma unroll
            for (int j = 0; j < 4; ++j)
                Ps[(tx * 4 + j) * 64 + ty * 4 + a] = pv[a][j];
        __syncthreads();

        // ---- acc += P V (4x4 per thread; i rows = ty*4.., d cols = tx*4..) ----
#pragma unroll 8
        for (int j = 0; j < 64; ++j) {
            float4 pa = *(const float4*)&Ps[j * 64 + ty * 4];
            float4 vv = *(const float4*)&Vs[j * 64 + tx * 4];
            float av[4] = {pa.x, pa.y, pa.z, pa.w};
            float bv[4] = {vv.x, vv.y, vv.z, vv.w};
#pragma unroll
            for (int i = 0; i < 4; ++i)
#pragma unroll
                for (int d = 0; d < 4; ++d)
                    acc[i][d] = fmaf(av[i], bv[d], acc[i][d]);
        }
    }

    // ---- normalize and write context ----
#pragma unroll
    for (int a = 0; a < 4; ++a) {
        float inv = 1.0f / lrow[a];
        int row = q0 + ty * 4 + a;
        float4 o;
        o.x = acc[a][0] * inv; o.y = acc[a][1] * inv;
        o.z = acc[a][2] * inv; o.w = acc[a][3] * inv;
        *(float4*)&O[(size_t)row * ROWSTRIDE + headoff + tx * 4] = o;
    }
}

// ---------------------------------------------------------------------------
// Inputs (setup_inputs order): hidden_states, attention_mask (ignored; causal),
// Wq, bq, Wk, bk, Wv, bv, Wo, bo. All fp32 except the bool mask.
// Output: [2048, 2, 1024] fp32.
// Workspace: Q (16MB) + K (16MB) + V (16MB) = 48MB; context aliases Q.
// ---------------------------------------------------------------------------
extern "C" void kernel_launch(void* const* d_in, const int* in_sizes, int n_in,
                              void* d_out, int out_size, void* d_ws, size_t ws_size,
                              hipStream_t stream) {
    const float* hs = (const float*)d_in[0];
    const float* Wq = (const float*)d_in[2];
    const float* bq = (const float*)d_in[3];
    const float* Wk = (const float*)d_in[4];
    const float* bk = (const float*)d_in[5];
    const float* Wv = (const float*)d_in[6];
    const float* bv = (const float*)d_in[7];
    const float* Wo = (const float*)d_in[8];
    const float* bo = (const float*)d_in[9];
    float* out = (float*)d_out;

    float* Qb = (float*)d_ws;
    float* Kb = Qb + (size_t)MROWS * HID;
    float* Vb = Kb + (size_t)MROWS * HID;
    float* ctx = Qb;  // alias: safe, see attn_fwd comment

    dim3 blk(256);
    dim3 gproj(MROWS / 64, HID / 64);

    // Q = (hs @ Wq^T + bq) / sqrt(64)
    hipLaunchKernelGGL(gemm_bt, gproj, blk, 0, stream, hs, Wq, bq, Qb,
                       MROWS, HID, HID, 0.125f);
    hipLaunchKernelGGL(gemm_bt, gproj, blk, 0, stream, hs, Wk, bk, Kb,
                       MROWS, HID, HID, 1.0f);
    hipLaunchKernelGGL(gemm_bt, gproj, blk, 0, stream, hs, Wv, bv, Vb,
                       MROWS, HID, HID, 1.0f);

    dim3 gattn(SEQ / 64, BATCH * NH);
    hipLaunchKernelGGL(attn_fwd, gattn, blk, 0, stream, Qb, Kb, Vb, ctx);

    // out = ctx @ Wo^T + bo
    hipLaunchKernelGGL(gemm_bt, gproj, blk, 0, stream, ctx, Wo, bo, out,
                       MROWS, HID, HID, 1.0f);
}

// Round 3
// 310.164 us; speedup vs baseline: 4.1565x; 4.1565x over previous
//
#include <hip/hip_runtime.h>
#include <hip/hip_bf16.h>
#include <cstdint>
#include <math.h>

#define SEQ 2048
#define BATCH 2
#define HID 1024
#define NH 16
#define HD 64
#define MROWS (SEQ * BATCH)  // 4096

typedef __attribute__((ext_vector_type(8))) short bf16x8;
typedef __attribute__((ext_vector_type(4))) float f32x4;

typedef const __attribute__((address_space(1))) void* gas_t;
typedef __attribute__((address_space(3))) void* las_t;

static __device__ __forceinline__ unsigned short f2bf(float x) {
    __hip_bfloat16 h = __float2bfloat16(x);  // RTNE
    unsigned short u;
    __builtin_memcpy(&u, &h, 2);
    return u;
}

// ---------------------------------------------------------------------------
// fp32 -> bf16 conversion, 8 elements/thread
// ---------------------------------------------------------------------------
__global__ __launch_bounds__(256) void f2bf_kern(const float* __restrict__ in,
                                                 unsigned short* __restrict__ out,
                                                 int n8) {
    int i = blockIdx.x * 256 + threadIdx.x;
    if (i >= n8) return;
    const float4* p = (const float4*)in + (size_t)i * 2;
    float4 a = p[0], b = p[1];
    union { unsigned short us[8]; uint4 v; } o;
    o.us[0] = f2bf(a.x); o.us[1] = f2bf(a.y); o.us[2] = f2bf(a.z); o.us[3] = f2bf(a.w);
    o.us[4] = f2bf(b.x); o.us[5] = f2bf(b.y); o.us[6] = f2bf(b.z); o.us[7] = f2bf(b.w);
    ((uint4*)out)[i] = o.v;
}

// ---------------------------------------------------------------------------
// bf16 MFMA GEMM: C = scale * (A @ W^T + bias)
// A:[M=4096][K=1024] bf16 row-major, W:[N=1024][K=1024] bf16 row-major.
// BM=64, BN=128, BK=32; 256 threads = 4 waves (2x2); wave tile 32x64.
// out_mode: 0 = bf16 natural [m][n]; 1 = bf16 V^T layout [n][b][s]
//           (n*4096 + (m&1)*2048 + (m>>1)); 2 = fp32 natural [m][n].
// ---------------------------------------------------------------------------
__global__ __launch_bounds__(256) void gemm_bf16(const unsigned short* __restrict__ A,
                                                 const unsigned short* __restrict__ W,
                                                 const float* __restrict__ bias,
                                                 void* __restrict__ Cout,
                                                 float scale, int out_mode) {
    __shared__ unsigned short As[64 * 32];    // [m][k] 4KB
    __shared__ unsigned short Bs[128 * 32];   // [n][k] 8KB
    const int t = threadIdx.x;
    const int lane = t & 63, w = t >> 6;
    const int wr = w & 1, wc = w >> 1;
    const int m0 = blockIdx.x * 64, n0 = blockIdx.y * 128;
    const int K = HID, N = HID;

    f32x4 acc[2][4];
#pragma unroll
    for (int i = 0; i < 2; ++i)
#pragma unroll
        for (int j = 0; j < 4; ++j) acc[i][j] = {0.f, 0.f, 0.f, 0.f};

    // staging addresses: lane l covers 16B = 8 bf16; chunk = 16 rows (1KB)
    const int srow = lane >> 2, skc = lane & 3;
    const unsigned short* gA  = A + (size_t)(m0 + w * 16 + srow) * K + skc * 8;
    const unsigned short* gB0 = W + (size_t)(n0 + (w * 2 + 0) * 16 + srow) * K + skc * 8;
    const unsigned short* gB1 = W + (size_t)(n0 + (w * 2 + 1) * 16 + srow) * K + skc * 8;
    unsigned short* lA  = As + w * 512;            // wave-uniform LDS bases
    unsigned short* lB0 = Bs + (w * 2 + 0) * 512;
    unsigned short* lB1 = Bs + (w * 2 + 1) * 512;

    const int arow = wr * 32 + (lane & 15);
    const int kfo = (lane >> 4) * 8;  // element offset of this lane's k-slice

    for (int k0 = 0; k0 < K; k0 += 32) {
        __syncthreads();
        __builtin_amdgcn_global_load_lds((gas_t)(gA + k0),  (las_t)lA,  16, 0, 0);
        __builtin_amdgcn_global_load_lds((gas_t)(gB0 + k0), (las_t)lB0, 16, 0, 0);
        __builtin_amdgcn_global_load_lds((gas_t)(gB1 + k0), (las_t)lB1, 16, 0, 0);
        __syncthreads();

        bf16x8 af[2], bfr[4];
#pragma unroll
        for (int mt = 0; mt < 2; ++mt)
            af[mt] = *(const bf16x8*)(As + (size_t)(arow + mt * 16) * 32 + kfo);
#pragma unroll
        for (int nt = 0; nt < 4; ++nt)
            bfr[nt] = *(const bf16x8*)(Bs + (size_t)(wc * 64 + nt * 16 + (lane & 15)) * 32 + kfo);
#pragma unroll
        for (int mt = 0; mt < 2; ++mt)
#pragma unroll
            for (int nt = 0; nt < 4; ++nt)
                acc[mt][nt] = __builtin_amdgcn_mfma_f32_16x16x32_bf16(
                    af[mt], bfr[nt], acc[mt][nt], 0, 0, 0);
    }

    float bvals[4];
#pragma unroll
    for (int nt = 0; nt < 4; ++nt)
        bvals[nt] = bias[n0 + wc * 64 + nt * 16 + (lane & 15)];

#pragma unroll
    for (int mt = 0; mt < 2; ++mt)
#pragma unroll
        for (int nt = 0; nt < 4; ++nt)
#pragma unroll
            for (int i = 0; i < 4; ++i) {
                float v = (acc[mt][nt][i] + bvals[nt]) * scale;
                int m = m0 + wr * 32 + mt * 16 + (lane >> 4) * 4 + i;
                int n = n0 + wc * 64 + nt * 16 + (lane & 15);
                if (out_mode == 0) {
                    ((unsigned short*)Cout)[(size_t)m * N + n] = f2bf(v);
                } else if (out_mode == 1) {
                    // V^T: [n][b][s] with m = s*2+b
                    ((unsigned short*)Cout)[(size_t)n * MROWS + (m & 1) * SEQ + (m >> 1)] = f2bf(v);
                } else {
                    ((float*)Cout)[(size_t)m * N + n] = v;
                }
            }
}

// ---------------------------------------------------------------------------
// Flash causal attention, bf16 MFMA. Grid (32 q-tiles, 32 b*h), 256 thr = 4 waves.
// Wave w owns S/O rows w*16..w*16+16 of the 64-row q-tile.
// Q:[m][1024] bf16 (pre-scaled 1/8), K:[m][1024] bf16, Vt:[n][b][s] bf16.
// LDS tiles XOR-swizzled: byte_in_row ^= (row&7)<<4  (rows are 128 B).
// ---------------------------------------------------------------------------
__global__ __launch_bounds__(256) void attn_mfma(const unsigned short* __restrict__ Qb,
                                                 const unsigned short* __restrict__ Kb,
                                                 const unsigned short* __restrict__ Vt,
                                                 unsigned short* __restrict__ Ob) {
    __shared__ unsigned short Kl[64 * 64];  // [j][d] swizzled
    __shared__ unsigned short Vl[64 * 64];  // [d][j] swizzled
    __shared__ unsigned short QP[64 * 64];  // Q then P, [r][c] swizzled

    const int t = threadIdx.x;
    const int lane = t & 63, w = t >> 6;
    const int qt = 31 - (int)blockIdx.x;          // heavy tiles first
    const int bh = blockIdx.y, b = bh >> 4, h = bh & 15;
    const int q0 = qt * 64;

    // ---- stage Q tile (reg -> swizzled LDS) ----
#pragma unroll
    for (int c = 0; c < 2; ++c) {
        int f = c * 256 + t;
        int r = f >> 3, dc = f & 7;
        uint4 v = *(const uint4*)(Qb + (size_t)((q0 + r) * 2 + b) * HID + h * 64 + dc * 8);
        *(uint4*)((char*)QP + r * 128 + ((dc * 16) ^ ((r & 7) << 4))) = v;
    }
    __syncthreads();

    // ---- hoist Q A-fragments (rows w*16+(lane&15), k = d) ----
    bf16x8 qf[2];
    {
        int r = w * 16 + (lane & 15);
        int base = r * 128, sw = (r & 7) << 4;
        qf[0] = *(const bf16x8*)((char*)QP + base + ((((lane >> 4) * 16) + 0) ^ sw));
        qf[1] = *(const bf16x8*)((char*)QP + base + ((((lane >> 4) * 16) + 64) ^ sw));
    }

    f32x4 acc[4];
#pragma unroll
    for (int nt = 0; nt < 4; ++nt) acc[nt] = {0.f, 0.f, 0.f, 0.f};
    float mrow[4] = {-INFINITY, -INFINITY, -INFINITY, -INFINITY};
    float lrow[4] = {0.f, 0.f, 0.f, 0.f};

    for (int kt = 0; kt <= qt; ++kt) {
        const int k0 = kt * 64;
        __syncthreads();  // previous iteration's Kl/Vl reads done
        // ---- stage K [j][d] and V^T [d][j] tiles ----
#pragma unroll
        for (int c = 0; c < 2; ++c) {
            int f = c * 256 + t;
            int r = f >> 3, cc = f & 7;
            uint4 kv = *(const uint4*)(Kb + (size_t)((k0 + r) * 2 + b) * HID + h * 64 + cc * 8);
            uint4 vv = *(const uint4*)(Vt + (size_t)(h * 64 + r) * MROWS + b * SEQ + k0 + cc * 8);
            int off = r * 128 + ((cc * 16) ^ ((r & 7) << 4));
            *(uint4*)((char*)Kl + off) = kv;
            *(uint4*)((char*)Vl + off) = vv;
        }
        __syncthreads();

        // ---- S = Q K^T : 4 col-tiles x (d-depth 64 = 2 MFMAs) ----
        f32x4 s[4];
#pragma unroll
        for (int ct = 0; ct < 4; ++ct) {
            int j = ct * 16 + (lane & 15);
            int base = j * 128, sw = (j & 7) << 4;
            bf16x8 kf0 = *(const bf16x8*)((char*)Kl + base + ((((lane >> 4) * 16) + 0) ^ sw));
            bf16x8 kf1 = *(const bf16x8*)((char*)Kl + base + ((((lane >> 4) * 16) + 64) ^ sw));
            f32x4 z = {0.f, 0.f, 0.f, 0.f};
            z = __builtin_amdgcn_mfma_f32_16x16x32_bf16(qf[0], kf0, z, 0, 0, 0);
            z = __builtin_amdgcn_mfma_f32_16x16x32_bf16(qf[1], kf1, z, 0, 0, 0);
            s[ct] = z;
        }

        // ---- causal mask on the diagonal tile ----
        if (kt == qt) {
#pragma unroll
            for (int ct = 0; ct < 4; ++ct) {
                int j = k0 + ct * 16 + (lane & 15);
#pragma unroll
                for (int i = 0; i < 4; ++i) {
                    int q = q0 + w * 16 + (lane >> 4) * 4 + i;
                    if (j > q) s[ct][i] = -3.0e38f;
                }
            }
        }

        // ---- online softmax (row r lives in 16 consecutive lanes) ----
#pragma unroll
        for (int i = 0; i < 4; ++i) {
            float mx = fmaxf(fmaxf(s[0][i], s[1][i]), fmaxf(s[2][i], s[3][i]));
            mx = fmaxf(mx, __shfl_xor(mx, 1));
            mx = fmaxf(mx, __shfl_xor(mx, 2));
            mx = fmaxf(mx, __shfl_xor(mx, 4));
            mx = fmaxf(mx, __shfl_xor(mx, 8));
            float mn = fmaxf(mrow[i], mx);
            float corr = __expf(mrow[i] - mn);
            mrow[i] = mn;
            float rs = 0.f;
#pragma unroll
            for (int ct = 0; ct < 4; ++ct) {
                float p = __expf(s[ct][i] - mn);
                s[ct][i] = p;
                rs += p;
            }
            rs += __shfl_xor(rs, 1);
            rs += __shfl_xor(rs, 2);
            rs += __shfl_xor(rs, 4);
            rs += __shfl_xor(rs, 8);
            lrow[i] = lrow[i] * corr + rs;
            // rescale ONLY component i of each accumulator (bug fix from R2:
            // acc[nt] *= corr scaled the whole f32x4 by every row's corr)
#pragma unroll
            for (int nt = 0; nt < 4; ++nt) acc[nt][i] *= corr;
        }

        // ---- P -> bf16 -> LDS (per-wave-private rows of QP) ----
#pragma unroll
        for (int ct = 0; ct < 4; ++ct)
#pragma unroll
            for (int i = 0; i < 4; ++i) {
                int r = w * 16 + (lane >> 4) * 4 + i;
                int jb = (ct * 16 + (lane & 15)) * 2;
                *(unsigned short*)((char*)QP + r * 128 + (jb ^ ((r & 7) << 4))) = f2bf(s[ct][i]);
            }
        asm volatile("s_waitcnt lgkmcnt(0)" ::: "memory");
        __builtin_amdgcn_sched_barrier(0);

        // ---- O += P V ----
        bf16x8 pf[2];
        {
            int r = w * 16 + (lane & 15);
            int base = r * 128, sw = (r & 7) << 4;
            pf[0] = *(const bf16x8*)((char*)QP + base + ((((lane >> 4) * 16) + 0) ^ sw));
            pf[1] = *(const bf16x8*)((char*)QP + base + ((((lane >> 4) * 16) + 64) ^ sw));
        }
#pragma unroll
        for (int nt = 0; nt < 4; ++nt) {
            int d = nt * 16 + (lane & 15);
            int base = d * 128, sw = (d & 7) << 4;
            bf16x8 v0 = *(const bf16x8*)((char*)Vl + base + ((((lane >> 4) * 16) + 0) ^ sw));
            bf16x8 v1 = *(const bf16x8*)((char*)Vl + base + ((((lane >> 4) * 16) + 64) ^ sw));
            acc[nt] = __builtin_amdgcn_mfma_f32_16x16x32_bf16(pf[0], v0, acc[nt], 0, 0, 0);
            acc[nt] = __builtin_amdgcn_mfma_f32_16x16x32_bf16(pf[1], v1, acc[nt], 0, 0, 0);
        }
    }

    // ---- normalize, write context (bf16 natural [m][1024]) ----
#pragma unroll
    for (int i = 0; i < 4; ++i) {
        float inv = 1.0f / lrow[i];
        int q = q0 + w * 16 + (lane >> 4) * 4 + i;
#pragma unroll
        for (int nt = 0; nt < 4; ++nt) {
            int col = h * 64 + nt * 16 + (lane & 15);
            Ob[(size_t)(q * 2 + b) * HID + col] = f2bf(acc[nt][i] * inv);
        }
    }
}

// ---------------------------------------------------------------------------
// Workspace layout (48 MB):
//  hs_bf 8MB | Wq_bf 2 | Wk_bf 2 | Wv_bf 2 | Wo_bf 2 | Q_bf 8 | K_bf 8 |
//  Vt_bf 8 | ctx_bf 8
// ---------------------------------------------------------------------------
extern "C" void kernel_launch(void* const* d_in, const int* in_sizes, int n_in,
                              void* d_out, int out_size, void* d_ws, size_t ws_size,
                              hipStream_t stream) {
    const float* hs = (const float*)d_in[0];
    const float* Wq = (const float*)d_in[2];
    const float* bq = (const float*)d_in[3];
    const float* Wk = (const float*)d_in[4];
    const float* bk = (const float*)d_in[5];
    const float* Wv = (const float*)d_in[6];
    const float* bv = (const float*)d_in[7];
    const float* Wo = (const float*)d_in[8];
    const float* bo = (const float*)d_in[9];

    char* ws = (char*)d_ws;
    unsigned short* hs_bf = (unsigned short*)(ws);
    unsigned short* Wq_bf = (unsigned short*)(ws + (8u << 20));
    unsigned short* Wk_bf = (unsigned short*)(ws + (10u << 20));
    unsigned short* Wv_bf = (unsigned short*)(ws + (12u << 20));
    unsigned short* Wo_bf = (unsigned short*)(ws + (14u << 20));
    unsigned short* Q_bf  = (unsigned short*)(ws + (16u << 20));
    unsigned short* K_bf  = (unsigned short*)(ws + (24u << 20));
    unsigned short* Vt_bf = (unsigned short*)(ws + (32u << 20));
    unsigned short* ctx_bf= (unsigned short*)(ws + (40u << 20));

    dim3 blk(256);
    // convert
    hipLaunchKernelGGL(f2bf_kern, dim3(MROWS * HID / 8 / 256), blk, 0, stream, hs, hs_bf, MROWS * HID / 8);
    hipLaunchKernelGGL(f2bf_kern, dim3(HID * HID / 8 / 256), blk, 0, stream, Wq, Wq_bf, HID * HID / 8);
    hipLaunchKernelGGL(f2bf_kern, dim3(HID * HID / 8 / 256), blk, 0, stream, Wk, Wk_bf, HID * HID / 8);
    hipLaunchKernelGGL(f2bf_kern, dim3(HID * HID / 8 / 256), blk, 0, stream, Wv, Wv_bf, HID * HID / 8);
    hipLaunchKernelGGL(f2bf_kern, dim3(HID * HID / 8 / 256), blk, 0, stream, Wo, Wo_bf, HID * HID / 8);

    dim3 gg(MROWS / 64, HID / 128);  // (64, 8)
    hipLaunchKernelGGL(gemm_bf16, gg, blk, 0, stream, hs_bf, Wq_bf, bq, (void*)Q_bf, 0.125f, 0);
    hipLaunchKernelGGL(gemm_bf16, gg, blk, 0, stream, hs_bf, Wk_bf, bk, (void*)K_bf, 1.0f, 0);
    hipLaunchKernelGGL(gemm_bf16, gg, blk, 0, stream, hs_bf, Wv_bf, bv, (void*)Vt_bf, 1.0f, 1);

    hipLaunchKernelGGL(attn_mfma, dim3(SEQ / 64, BATCH * NH), blk, 0, stream,
                       Q_bf, K_bf, Vt_bf, ctx_bf);

    hipLaunchKernelGGL(gemm_bf16, gg, blk, 0, stream, ctx_bf, Wo_bf, bo, d_out, 1.0f, 2);
}

// Round 4
// 291.652 us; speedup vs baseline: 4.4203x; 1.0635x over previous
//
#include <hip/hip_runtime.h>
#include <hip/hip_bf16.h>
#include <cstdint>
#include <math.h>

#define SEQ 2048
#define BATCH 2
#define HID 1024
#define NH 16
#define HD 64
#define MROWS (SEQ * BATCH)  // 4096

typedef __attribute__((ext_vector_type(8))) short bf16x8;
typedef __attribute__((ext_vector_type(4))) float f32x4;

typedef const __attribute__((address_space(1))) void* gas_t;
typedef __attribute__((address_space(3))) void* las_t;

static __device__ __forceinline__ unsigned short f2bf(float x) {
    __hip_bfloat16 h = __float2bfloat16(x);  // RTNE
    unsigned short u;
    __builtin_memcpy(&u, &h, 2);
    return u;
}

// ---------------------------------------------------------------------------
// fp32 -> bf16 conversion, 8 elements/thread
// ---------------------------------------------------------------------------
__global__ __launch_bounds__(256) void f2bf_kern(const float* __restrict__ in,
                                                 unsigned short* __restrict__ out,
                                                 int n8) {
    int i = blockIdx.x * 256 + threadIdx.x;
    if (i >= n8) return;
    const float4* p = (const float4*)in + (size_t)i * 2;
    float4 a = p[0], b = p[1];
    union { unsigned short us[8]; uint4 v; } o;
    o.us[0] = f2bf(a.x); o.us[1] = f2bf(a.y); o.us[2] = f2bf(a.z); o.us[3] = f2bf(a.w);
    o.us[4] = f2bf(b.x); o.us[5] = f2bf(b.y); o.us[6] = f2bf(b.z); o.us[7] = f2bf(b.w);
    ((uint4*)out)[i] = o.v;
}

// ---------------------------------------------------------------------------
// bf16 MFMA GEMM (m97-class): C = scale * (A @ W^T + bias)
// BM=BN=128, BK=32; 256 thr = 4 waves (2x2), wave tile 64x64, acc 4x4 frags.
// Double-buffered LDS (32KB), 2-phase prefetch: stage(kt+1) issued before
// compute(kt); single __syncthreads()/iter (its implicit vmcnt/lgkm drain is
// the wait for the buffer staged last iteration).
// out_mode: 0 = bf16 [m][n]; 1 = bf16 V^T [n][b][s]; 2 = fp32 [m][n].
// ---------------------------------------------------------------------------
#define GBK 32

__global__ __launch_bounds__(256) void gemm_bf16(const unsigned short* __restrict__ A,
                                                 const unsigned short* __restrict__ W,
                                                 const float* __restrict__ bias,
                                                 void* __restrict__ Cout,
                                                 float scale, int out_mode) {
    __shared__ unsigned short As[2][128 * GBK];  // [m][k] 8KB each
    __shared__ unsigned short Bs[2][128 * GBK];  // [n][k] 8KB each
    const int t = threadIdx.x;
    const int lane = t & 63, w = t >> 6;
    const int wr = w & 1, wc = w >> 1;
    const int m0 = blockIdx.x * 128, n0 = blockIdx.y * 128;

    f32x4 acc[4][4];
#pragma unroll
    for (int i = 0; i < 4; ++i)
#pragma unroll
        for (int j = 0; j < 4; ++j) acc[i][j] = {0.f, 0.f, 0.f, 0.f};

    // staging: call c covers rows c*64 + w*16 + (lane>>2), 16B chunk lane&3
    const int srow = w * 16 + (lane >> 2);
    const int scol = (lane & 3) * 8;
    const unsigned short* gA = A + (size_t)(m0 + srow) * HID + scol;
    const unsigned short* gB = W + (size_t)(n0 + srow) * HID + scol;

    auto stage = [&](int buf, int k0) {
#pragma unroll
        for (int c = 0; c < 2; ++c) {
            __builtin_amdgcn_global_load_lds((gas_t)(gA + (size_t)c * 64 * HID + k0),
                                             (las_t)(&As[buf][(c * 64 + w * 16) * GBK]), 16, 0, 0);
            __builtin_amdgcn_global_load_lds((gas_t)(gB + (size_t)c * 64 * HID + k0),
                                             (las_t)(&Bs[buf][(c * 64 + w * 16) * GBK]), 16, 0, 0);
        }
    };

    const int arow = wr * 64 + (lane & 15);
    const int brow = wc * 64 + (lane & 15);
    const int kfo = (lane >> 4) * 8;

    stage(0, 0);
    int cur = 0;
    for (int k0 = 0; k0 < HID; k0 += GBK) {
        __syncthreads();  // drains vmcnt: buf[cur] ready; buf[cur^1] reads done
        if (k0 + GBK < HID) stage(cur ^ 1, k0 + GBK);
        bf16x8 af[4], bfr[4];
#pragma unroll
        for (int mt = 0; mt < 4; ++mt)
            af[mt] = *(const bf16x8*)(&As[cur][(arow + mt * 16) * GBK + kfo]);
#pragma unroll
        for (int nt = 0; nt < 4; ++nt)
            bfr[nt] = *(const bf16x8*)(&Bs[cur][(brow + nt * 16) * GBK + kfo]);
#pragma unroll
        for (int mt = 0; mt < 4; ++mt)
#pragma unroll
            for (int nt = 0; nt < 4; ++nt)
                acc[mt][nt] = __builtin_amdgcn_mfma_f32_16x16x32_bf16(
                    af[mt], bfr[nt], acc[mt][nt], 0, 0, 0);
        cur ^= 1;
    }

    float bvals[4];
#pragma unroll
    for (int nt = 0; nt < 4; ++nt)
        bvals[nt] = bias[n0 + wc * 64 + nt * 16 + (lane & 15)];

#pragma unroll
    for (int mt = 0; mt < 4; ++mt)
#pragma unroll
        for (int nt = 0; nt < 4; ++nt)
#pragma unroll
            for (int i = 0; i < 4; ++i) {
                float v = (acc[mt][nt][i] + bvals[nt]) * scale;
                int m = m0 + wr * 64 + mt * 16 + (lane >> 4) * 4 + i;
                int n = n0 + wc * 64 + nt * 16 + (lane & 15);
                if (out_mode == 0) {
                    ((unsigned short*)Cout)[(size_t)m * HID + n] = f2bf(v);
                } else if (out_mode == 1) {
                    ((unsigned short*)Cout)[(size_t)n * MROWS + (m & 1) * SEQ + (m >> 1)] = f2bf(v);
                } else {
                    ((float*)Cout)[(size_t)m * HID + n] = v;
                }
            }
}

// ---------------------------------------------------------------------------
// Flash causal attention, bf16 MFMA, load-balanced + pipelined.
// Grid (16, 32) = 512 uniform blocks; block handles q-tiles (31-p) then (p):
// exactly 33 tile-iterations each -> no causal tail. 256 thr = 4 waves, wave
// owns rows w*16..+16 of the 64-row q-tile.
// K/V double-buffered in LDS, staged via global_load_lds with PRE-SWIZZLED
// global source (linear dest + inverse-swz src + swz read; XOR involution
// byte^=(row&7)<<4 on 128B rows). One __syncthreads()/iter; its implicit
// vmcnt(0) drain waits for the loads issued the previous iteration.
// XCD-clustered bh mapping: 16 blocks sharing one (b,h)'s K/V land on 2
// XCD-groups (4 bh/XCD * 512KB = 2MB < 4MB L2).
// ---------------------------------------------------------------------------
__global__ __launch_bounds__(256) void attn_mfma(const unsigned short* __restrict__ Qb,
                                                 const unsigned short* __restrict__ Kb,
                                                 const unsigned short* __restrict__ Vt,
                                                 unsigned short* __restrict__ Ob) {
    __shared__ unsigned short Kl[2][64 * 64];  // [j][d] swizzled, 8KB each
    __shared__ unsigned short Vl[2][64 * 64];  // [d][j] swizzled, 8KB each
    __shared__ unsigned short QP[64 * 64];     // Q then P, swizzled, 8KB

    const int t = threadIdx.x;
    const int lane = t & 63, w = t >> 6;

    // XCD-clustered swizzle of (p, bh)
    const int flat = (int)blockIdx.x + (int)blockIdx.y * 16;
    const int xcd = flat & 7, ii = flat >> 3;
    const int bh = xcd * 4 + (ii >> 4);
    const int p = ii & 15;
    const int b = bh >> 4, h = bh & 15;

    // per-lane staging geometry (shared by K and V tiles): call c covers local
    // rows c*32 + w*8 + (lane>>3); 16B chunk lane&7 of the 128B row.
    const int lrow_base = w * 8 + (lane >> 3);
    const int chunkb = (lane & 7) * 16;

    for (int pass = 0; pass < 2; ++pass) {
        const int qt = pass == 0 ? (31 - p) : p;
        const int q0 = qt * 64;
        if (pass) __syncthreads();  // QP + K/V buffers safe to reuse

        auto stage_kv = [&](int buf, int kt) {
            const int k0 = kt * 64;
#pragma unroll
            for (int c = 0; c < 2; ++c) {
                int lr = c * 32 + lrow_base;            // local row 0..63
                int sb = chunkb ^ ((lr & 7) << 4);      // pre-swizzled byte
                // K: row j -> global row (k0+lr), head slice h*64
                const unsigned short* ksrc =
                    Kb + ((size_t)(k0 + lr) * 2 + b) * HID + h * 64 + (sb >> 1);
                // V^T: row d -> global row (h*64+lr), cols k0.. of [n][b][s]
                const unsigned short* vsrc =
                    Vt + (size_t)(h * 64 + lr) * MROWS + b * SEQ + k0 + (sb >> 1);
                __builtin_amdgcn_global_load_lds((gas_t)ksrc,
                    (las_t)(&Kl[buf][(c * 32 + w * 8) * 64]), 16, 0, 0);
                __builtin_amdgcn_global_load_lds((gas_t)vsrc,
                    (las_t)(&Vl[buf][(c * 32 + w * 8) * 64]), 16, 0, 0);
            }
        };

        stage_kv(0, 0);  // in flight during Q staging

        // ---- stage Q tile (reg -> swizzled LDS) ----
#pragma unroll
        for (int c = 0; c < 2; ++c) {
            int f = c * 256 + t;
            int r = f >> 3, dc = f & 7;
            uint4 v = *(const uint4*)(Qb + (size_t)((q0 + r) * 2 + b) * HID + h * 64 + dc * 8);
            *(uint4*)((char*)QP + r * 128 + ((dc * 16) ^ ((r & 7) << 4))) = v;
        }

        f32x4 acc[4];
#pragma unroll
        for (int nt = 0; nt < 4; ++nt) acc[nt] = {0.f, 0.f, 0.f, 0.f};
        float mrow[4] = {-INFINITY, -INFINITY, -INFINITY, -INFINITY};
        float lrow[4] = {0.f, 0.f, 0.f, 0.f};
        bf16x8 qf[2];

        int cur = 0;
        for (int kt = 0; kt <= qt; ++kt) {
            __syncthreads();  // drains vmcnt: Kl/Vl[cur] staged; lgkm: Q/P writes
            if (kt < qt) stage_kv(cur ^ 1, kt + 1);
            if (kt == 0) {
                // hoist Q A-fragments (before P overwrites QP)
                int r = w * 16 + (lane & 15);
                int base = r * 128, sw = (r & 7) << 4;
                qf[0] = *(const bf16x8*)((char*)QP + base + ((((lane >> 4) * 16) + 0) ^ sw));
                qf[1] = *(const bf16x8*)((char*)QP + base + ((((lane >> 4) * 16) + 64) ^ sw));
            }
            const char* Kc = (const char*)Kl[cur];
            const char* Vc = (const char*)Vl[cur];

            // ---- S = Q K^T ----
            f32x4 s[4];
#pragma unroll
            for (int ct = 0; ct < 4; ++ct) {
                int j = ct * 16 + (lane & 15);
                int base = j * 128, sw = (j & 7) << 4;
                bf16x8 kf0 = *(const bf16x8*)(Kc + base + ((((lane >> 4) * 16) + 0) ^ sw));
                bf16x8 kf1 = *(const bf16x8*)(Kc + base + ((((lane >> 4) * 16) + 64) ^ sw));
                f32x4 z = {0.f, 0.f, 0.f, 0.f};
                z = __builtin_amdgcn_mfma_f32_16x16x32_bf16(qf[0], kf0, z, 0, 0, 0);
                z = __builtin_amdgcn_mfma_f32_16x16x32_bf16(qf[1], kf1, z, 0, 0, 0);
                s[ct] = z;
            }

            // ---- causal mask on diagonal tile ----
            if (kt == qt) {
#pragma unroll
                for (int ct = 0; ct < 4; ++ct) {
                    int j = ct * 16 + (lane & 15);
#pragma unroll
                    for (int i = 0; i < 4; ++i) {
                        int q = w * 16 + (lane >> 4) * 4 + i;
                        if (j > q) s[ct][i] = -3.0e38f;
                    }
                }
            }

            // ---- online softmax (row lives in 16 consecutive lanes) ----
#pragma unroll
            for (int i = 0; i < 4; ++i) {
                float mx = fmaxf(fmaxf(s[0][i], s[1][i]), fmaxf(s[2][i], s[3][i]));
                mx = fmaxf(mx, __shfl_xor(mx, 1));
                mx = fmaxf(mx, __shfl_xor(mx, 2));
                mx = fmaxf(mx, __shfl_xor(mx, 4));
                mx = fmaxf(mx, __shfl_xor(mx, 8));
                float mn = fmaxf(mrow[i], mx);
                float corr = __expf(mrow[i] - mn);
                mrow[i] = mn;
                float rs = 0.f;
#pragma unroll
                for (int ct = 0; ct < 4; ++ct) {
                    float pe = __expf(s[ct][i] - mn);
                    s[ct][i] = pe;
                    rs += pe;
                }
                rs += __shfl_xor(rs, 1);
                rs += __shfl_xor(rs, 2);
                rs += __shfl_xor(rs, 4);
                rs += __shfl_xor(rs, 8);
                lrow[i] = lrow[i] * corr + rs;
#pragma unroll
                for (int nt = 0; nt < 4; ++nt) acc[nt][i] *= corr;
            }

            // ---- P -> bf16 -> LDS (wave-private rows of QP) ----
#pragma unroll
            for (int ct = 0; ct < 4; ++ct)
#pragma unroll
                for (int i = 0; i < 4; ++i) {
                    int r = w * 16 + (lane >> 4) * 4 + i;
                    int jb = (ct * 16 + (lane & 15)) * 2;
                    *(unsigned short*)((char*)QP + r * 128 + (jb ^ ((r & 7) << 4))) = f2bf(s[ct][i]);
                }
            asm volatile("s_waitcnt lgkmcnt(0)" ::: "memory");
            __builtin_amdgcn_sched_barrier(0);

            // ---- O += P V ----
            bf16x8 pf[2];
            {
                int r = w * 16 + (lane & 15);
                int base = r * 128, sw = (r & 7) << 4;
                pf[0] = *(const bf16x8*)((char*)QP + base + ((((lane >> 4) * 16) + 0) ^ sw));
                pf[1] = *(const bf16x8*)((char*)QP + base + ((((lane >> 4) * 16) + 64) ^ sw));
            }
#pragma unroll
            for (int nt = 0; nt < 4; ++nt) {
                int d = nt * 16 + (lane & 15);
                int base = d * 128, sw = (d & 7) << 4;
                bf16x8 v0 = *(const bf16x8*)(Vc + base + ((((lane >> 4) * 16) + 0) ^ sw));
                bf16x8 v1 = *(const bf16x8*)(Vc + base + ((((lane >> 4) * 16) + 64) ^ sw));
                acc[nt] = __builtin_amdgcn_mfma_f32_16x16x32_bf16(pf[0], v0, acc[nt], 0, 0, 0);
                acc[nt] = __builtin_amdgcn_mfma_f32_16x16x32_bf16(pf[1], v1, acc[nt], 0, 0, 0);
            }
            cur ^= 1;
        }

        // ---- normalize, write context ----
#pragma unroll
        for (int i = 0; i < 4; ++i) {
            float inv = 1.0f / lrow[i];
            int q = q0 + w * 16 + (lane >> 4) * 4 + i;
#pragma unroll
            for (int nt = 0; nt < 4; ++nt) {
                int col = h * 64 + nt * 16 + (lane & 15);
                Ob[(size_t)(q * 2 + b) * HID + col] = f2bf(acc[nt][i] * inv);
            }
        }
    }
}

// ---------------------------------------------------------------------------
// Workspace layout (48 MB):
//  hs_bf 8MB | Wq_bf 2 | Wk_bf 2 | Wv_bf 2 | Wo_bf 2 | Q_bf 8 | K_bf 8 |
//  Vt_bf 8 | ctx_bf 8
// ---------------------------------------------------------------------------
extern "C" void kernel_launch(void* const* d_in, const int* in_sizes, int n_in,
                              void* d_out, int out_size, void* d_ws, size_t ws_size,
                              hipStream_t stream) {
    const float* hs = (const float*)d_in[0];
    const float* Wq = (const float*)d_in[2];
    const float* bq = (const float*)d_in[3];
    const float* Wk = (const float*)d_in[4];
    const float* bk = (const float*)d_in[5];
    const float* Wv = (const float*)d_in[6];
    const float* bv = (const float*)d_in[7];
    const float* Wo = (const float*)d_in[8];
    const float* bo = (const float*)d_in[9];

    char* ws = (char*)d_ws;
    unsigned short* hs_bf = (unsigned short*)(ws);
    unsigned short* Wq_bf = (unsigned short*)(ws + (8u << 20));
    unsigned short* Wk_bf = (unsigned short*)(ws + (10u << 20));
    unsigned short* Wv_bf = (unsigned short*)(ws + (12u << 20));
    unsigned short* Wo_bf = (unsigned short*)(ws + (14u << 20));
    unsigned short* Q_bf  = (unsigned short*)(ws + (16u << 20));
    unsigned short* K_bf  = (unsigned short*)(ws + (24u << 20));
    unsigned short* Vt_bf = (unsigned short*)(ws + (32u << 20));
    unsigned short* ctx_bf= (unsigned short*)(ws + (40u << 20));

    dim3 blk(256);
    hipLaunchKernelGGL(f2bf_kern, dim3(MROWS * HID / 8 / 256), blk, 0, stream, hs, hs_bf, MROWS * HID / 8);
    hipLaunchKernelGGL(f2bf_kern, dim3(HID * HID / 8 / 256), blk, 0, stream, Wq, Wq_bf, HID * HID / 8);
    hipLaunchKernelGGL(f2bf_kern, dim3(HID * HID / 8 / 256), blk, 0, stream, Wk, Wk_bf, HID * HID / 8);
    hipLaunchKernelGGL(f2bf_kern, dim3(HID * HID / 8 / 256), blk, 0, stream, Wv, Wv_bf, HID * HID / 8);
    hipLaunchKernelGGL(f2bf_kern, dim3(HID * HID / 8 / 256), blk, 0, stream, Wo, Wo_bf, HID * HID / 8);

    dim3 gg(MROWS / 128, HID / 128);  // (32, 8) = 256 blocks
    hipLaunchKernelGGL(gemm_bf16, gg, blk, 0, stream, hs_bf, Wq_bf, bq, (void*)Q_bf, 0.125f, 0);
    hipLaunchKernelGGL(gemm_bf16, gg, blk, 0, stream, hs_bf, Wk_bf, bk, (void*)K_bf, 1.0f, 0);
    hipLaunchKernelGGL(gemm_bf16, gg, blk, 0, stream, hs_bf, Wv_bf, bv, (void*)Vt_bf, 1.0f, 1);

    hipLaunchKernelGGL(attn_mfma, dim3(16, 32), blk, 0, stream,
                       Q_bf, K_bf, Vt_bf, ctx_bf);

    hipLaunchKernelGGL(gemm_bf16, gg, blk, 0, stream, ctx_bf, Wo_bf, bo, d_out, 1.0f, 2);
}

// Round 5
// 245.738 us; speedup vs baseline: 5.2462x; 1.1868x over previous
//
#include <hip/hip_runtime.h>
#include <hip/hip_bf16.h>
#include <cstdint>
#include <math.h>

#define SEQ 2048
#define BATCH 2
#define HID 1024
#define NH 16
#define HD 64
#define MROWS (SEQ * BATCH)  // 4096

typedef __attribute__((ext_vector_type(8))) short bf16x8;
typedef __attribute__((ext_vector_type(4))) float f32x4;

typedef const __attribute__((address_space(1))) void* gas_t;
typedef __attribute__((address_space(3))) void* las_t;

static __device__ __forceinline__ unsigned short f2bf(float x) {
    __hip_bfloat16 h = __float2bfloat16(x);  // RTNE
    unsigned short u;
    __builtin_memcpy(&u, &h, 2);
    return u;
}

// ---------------------------------------------------------------------------
// fp32 -> bf16 conversion, 8 elements/thread
// ---------------------------------------------------------------------------
__global__ __launch_bounds__(256) void f2bf_kern(const float* __restrict__ in,
                                                 unsigned short* __restrict__ out,
                                                 int n8) {
    int i = blockIdx.x * 256 + threadIdx.x;
    if (i >= n8) return;
    const float4* p = (const float4*)in + (size_t)i * 2;
    float4 a = p[0], b = p[1];
    union { unsigned short us[8]; uint4 v; } o;
    o.us[0] = f2bf(a.x); o.us[1] = f2bf(a.y); o.us[2] = f2bf(a.z); o.us[3] = f2bf(a.w);
    o.us[4] = f2bf(b.x); o.us[5] = f2bf(b.y); o.us[6] = f2bf(b.z); o.us[7] = f2bf(b.w);
    ((uint4*)out)[i] = o.v;
}

// ---------------------------------------------------------------------------
// bf16 MFMA GEMM, BM=64 BN=128 BK=32, 256 thr = 4 waves (2x2), wave tile
// 32x64 (acc 2x4 frags). Double-buffered LDS (24KB), single-barrier 2-phase
// pipeline: stage(kt+1) issued right after the barrier, before compute(kt);
// the next barrier's implicit vmcnt(0) drain is the wait.
// mode 0 (QKV fused, N=3072): n-segment 0 -> Q bf16 [m][1024] scaled 1/8,
//   seg 1 -> K bf16 [m][1024], seg 2 -> V^T bf16 [n][b][s]  (m = s*2+b).
// mode 1 (Wo, N=1024): fp32 natural [m][1024], bias b0.
// Occupancy: QKV grid (64,24)=1536 blocks = 6/CU (LDS-capped); Wo (64,8)=512.
// ---------------------------------------------------------------------------
#define GBK 32

__global__ __launch_bounds__(256, 4) void gemm_bf16(
    const unsigned short* __restrict__ A, const unsigned short* __restrict__ W,
    const float* __restrict__ b0, const float* __restrict__ b1,
    const float* __restrict__ b2,
    unsigned short* __restrict__ Qo, unsigned short* __restrict__ Ko,
    unsigned short* __restrict__ Vo, float* __restrict__ Fo, int mode) {
    __shared__ unsigned short As[2][64 * GBK];    // [m][k] 4KB each
    __shared__ unsigned short Bs[2][128 * GBK];   // [n][k] 8KB each
    const int t = threadIdx.x;
    const int lane = t & 63, w = t >> 6;
    const int wr = w & 1, wc = w >> 1;
    const int m0 = blockIdx.x * 64, n0 = blockIdx.y * 128;

    f32x4 acc[2][4];
#pragma unroll
    for (int i = 0; i < 2; ++i)
#pragma unroll
        for (int j = 0; j < 4; ++j) acc[i][j] = {0.f, 0.f, 0.f, 0.f};

    // staging: thread covers row w*16+(lane>>2) (+c*64 for B), 16B chunk lane&3
    const int srow = w * 16 + (lane >> 2);
    const int scol = (lane & 3) * 8;
    const unsigned short* gA = A + (size_t)(m0 + srow) * HID + scol;
    const unsigned short* gB = W + (size_t)(n0 + srow) * HID + scol;

    auto stage = [&](int buf, int k0) {
        __builtin_amdgcn_global_load_lds((gas_t)(gA + k0),
                                         (las_t)(&As[buf][(w * 16) * GBK]), 16, 0, 0);
#pragma unroll
        for (int c = 0; c < 2; ++c)
            __builtin_amdgcn_global_load_lds((gas_t)(gB + (size_t)c * 64 * HID + k0),
                                             (las_t)(&Bs[buf][(c * 64 + w * 16) * GBK]), 16, 0, 0);
    };

    const int arow = wr * 32 + (lane & 15);
    const int brow = wc * 64 + (lane & 15);
    const int kfo = (lane >> 4) * 8;

    stage(0, 0);
    int cur = 0;
    for (int k0 = 0; k0 < HID; k0 += GBK) {
        __syncthreads();  // drains vmcnt: buf[cur] ready; buf[cur^1] reads done
        if (k0 + GBK < HID) stage(cur ^ 1, k0 + GBK);
        bf16x8 af[2], bfr[4];
#pragma unroll
        for (int mt = 0; mt < 2; ++mt)
            af[mt] = *(const bf16x8*)(&As[cur][(arow + mt * 16) * GBK + kfo]);
#pragma unroll
        for (int nt = 0; nt < 4; ++nt)
            bfr[nt] = *(const bf16x8*)(&Bs[cur][(brow + nt * 16) * GBK + kfo]);
#pragma unroll
        for (int mt = 0; mt < 2; ++mt)
#pragma unroll
            for (int nt = 0; nt < 4; ++nt)
                acc[mt][nt] = __builtin_amdgcn_mfma_f32_16x16x32_bf16(
                    af[mt], bfr[nt], acc[mt][nt], 0, 0, 0);
        cur ^= 1;
    }

    // ---- epilogue: segment-uniform per block ----
    const int seg = n0 >> 10;  // 0=Q 1=K 2=V (mode 0); 0 for mode 1
    const float* bias = (mode == 1) ? b0 : (seg == 0 ? b0 : (seg == 1 ? b1 : b2));
    const float scale = (mode == 0 && seg == 0) ? 0.125f : 1.0f;
    const int nbase = (n0 & 1023) + wc * 64;

    float bvals[4];
#pragma unroll
    for (int nt = 0; nt < 4; ++nt)
        bvals[nt] = bias[nbase + nt * 16 + (lane & 15)];

#pragma unroll
    for (int mt = 0; mt < 2; ++mt)
#pragma unroll
        for (int nt = 0; nt < 4; ++nt)
#pragma unroll
            for (int i = 0; i < 4; ++i) {
                float v = (acc[mt][nt][i] + bvals[nt]) * scale;
                int m = m0 + wr * 32 + mt * 16 + (lane >> 4) * 4 + i;
                int n = nbase + nt * 16 + (lane & 15);  // within-segment col
                if (mode == 1) {
                    Fo[(size_t)m * HID + n] = v;
                } else if (seg == 0) {
                    Qo[(size_t)m * HID + n] = f2bf(v);
                } else if (seg == 1) {
                    Ko[(size_t)m * HID + n] = f2bf(v);
                } else {
                    Vo[(size_t)n * MROWS + (m & 1) * SEQ + (m >> 1)] = f2bf(v);
                }
            }
}

// ---------------------------------------------------------------------------
// Flash causal attention, bf16 MFMA, load-balanced + pipelined (unchanged
// from R4: 79us, MfmaUtil 8.5%, conflicts 0).
// Grid (16, 32) = 512 uniform blocks; block handles q-tiles (31-p) then (p).
// ---------------------------------------------------------------------------
__global__ __launch_bounds__(256) void attn_mfma(const unsigned short* __restrict__ Qb,
                                                 const unsigned short* __restrict__ Kb,
                                                 const unsigned short* __restrict__ Vt,
                                                 unsigned short* __restrict__ Ob) {
    __shared__ unsigned short Kl[2][64 * 64];  // [j][d] swizzled, 8KB each
    __shared__ unsigned short Vl[2][64 * 64];  // [d][j] swizzled, 8KB each
    __shared__ unsigned short QP[64 * 64];     // Q then P, swizzled, 8KB

    const int t = threadIdx.x;
    const int lane = t & 63, w = t >> 6;

    const int flat = (int)blockIdx.x + (int)blockIdx.y * 16;
    const int xcd = flat & 7, ii = flat >> 3;
    const int bh = xcd * 4 + (ii >> 4);
    const int p = ii & 15;
    const int b = bh >> 4, h = bh & 15;

    const int lrow_base = w * 8 + (lane >> 3);
    const int chunkb = (lane & 7) * 16;

    for (int pass = 0; pass < 2; ++pass) {
        const int qt = pass == 0 ? (31 - p) : p;
        const int q0 = qt * 64;
        if (pass) __syncthreads();

        auto stage_kv = [&](int buf, int kt) {
            const int k0 = kt * 64;
#pragma unroll
            for (int c = 0; c < 2; ++c) {
                int lr = c * 32 + lrow_base;
                int sb = chunkb ^ ((lr & 7) << 4);
                const unsigned short* ksrc =
                    Kb + ((size_t)(k0 + lr) * 2 + b) * HID + h * 64 + (sb >> 1);
                const unsigned short* vsrc =
                    Vt + (size_t)(h * 64 + lr) * MROWS + b * SEQ + k0 + (sb >> 1);
                __builtin_amdgcn_global_load_lds((gas_t)ksrc,
                    (las_t)(&Kl[buf][(c * 32 + w * 8) * 64]), 16, 0, 0);
                __builtin_amdgcn_global_load_lds((gas_t)vsrc,
                    (las_t)(&Vl[buf][(c * 32 + w * 8) * 64]), 16, 0, 0);
            }
        };

        stage_kv(0, 0);

#pragma unroll
        for (int c = 0; c < 2; ++c) {
            int f = c * 256 + t;
            int r = f >> 3, dc = f & 7;
            uint4 v = *(const uint4*)(Qb + (size_t)((q0 + r) * 2 + b) * HID + h * 64 + dc * 8);
            *(uint4*)((char*)QP + r * 128 + ((dc * 16) ^ ((r & 7) << 4))) = v;
        }

        f32x4 acc[4];
#pragma unroll
        for (int nt = 0; nt < 4; ++nt) acc[nt] = {0.f, 0.f, 0.f, 0.f};
        float mrow[4] = {-INFINITY, -INFINITY, -INFINITY, -INFINITY};
        float lrow[4] = {0.f, 0.f, 0.f, 0.f};
        bf16x8 qf[2];

        int cur = 0;
        for (int kt = 0; kt <= qt; ++kt) {
            __syncthreads();
            if (kt < qt) stage_kv(cur ^ 1, kt + 1);
            if (kt == 0) {
                int r = w * 16 + (lane & 15);
                int base = r * 128, sw = (r & 7) << 4;
                qf[0] = *(const bf16x8*)((char*)QP + base + ((((lane >> 4) * 16) + 0) ^ sw));
                qf[1] = *(const bf16x8*)((char*)QP + base + ((((lane >> 4) * 16) + 64) ^ sw));
            }
            const char* Kc = (const char*)Kl[cur];
            const char* Vc = (const char*)Vl[cur];

            f32x4 s[4];
#pragma unroll
            for (int ct = 0; ct < 4; ++ct) {
                int j = ct * 16 + (lane & 15);
                int base = j * 128, sw = (j & 7) << 4;
                bf16x8 kf0 = *(const bf16x8*)(Kc + base + ((((lane >> 4) * 16) + 0) ^ sw));
                bf16x8 kf1 = *(const bf16x8*)(Kc + base + ((((lane >> 4) * 16) + 64) ^ sw));
                f32x4 z = {0.f, 0.f, 0.f, 0.f};
                z = __builtin_amdgcn_mfma_f32_16x16x32_bf16(qf[0], kf0, z, 0, 0, 0);
                z = __builtin_amdgcn_mfma_f32_16x16x32_bf16(qf[1], kf1, z, 0, 0, 0);
                s[ct] = z;
            }

            if (kt == qt) {
#pragma unroll
                for (int ct = 0; ct < 4; ++ct) {
                    int j = ct * 16 + (lane & 15);
#pragma unroll
                    for (int i = 0; i < 4; ++i) {
                        int q = w * 16 + (lane >> 4) * 4 + i;
                        if (j > q) s[ct][i] = -3.0e38f;
                    }
                }
            }

#pragma unroll
            for (int i = 0; i < 4; ++i) {
                float mx = fmaxf(fmaxf(s[0][i], s[1][i]), fmaxf(s[2][i], s[3][i]));
                mx = fmaxf(mx, __shfl_xor(mx, 1));
                mx = fmaxf(mx, __shfl_xor(mx, 2));
                mx = fmaxf(mx, __shfl_xor(mx, 4));
                mx = fmaxf(mx, __shfl_xor(mx, 8));
                float mn = fmaxf(mrow[i], mx);
                float corr = __expf(mrow[i] - mn);
                mrow[i] = mn;
                float rs = 0.f;
#pragma unroll
                for (int ct = 0; ct < 4; ++ct) {
                    float pe = __expf(s[ct][i] - mn);
                    s[ct][i] = pe;
                    rs += pe;
                }
                rs += __shfl_xor(rs, 1);
                rs += __shfl_xor(rs, 2);
                rs += __shfl_xor(rs, 4);
                rs += __shfl_xor(rs, 8);
                lrow[i] = lrow[i] * corr + rs;
#pragma unroll
                for (int nt = 0; nt < 4; ++nt) acc[nt][i] *= corr;
            }

#pragma unroll
            for (int ct = 0; ct < 4; ++ct)
#pragma unroll
                for (int i = 0; i < 4; ++i) {
                    int r = w * 16 + (lane >> 4) * 4 + i;
                    int jb = (ct * 16 + (lane & 15)) * 2;
                    *(unsigned short*)((char*)QP + r * 128 + (jb ^ ((r & 7) << 4))) = f2bf(s[ct][i]);
                }
            asm volatile("s_waitcnt lgkmcnt(0)" ::: "memory");
            __builtin_amdgcn_sched_barrier(0);

            bf16x8 pf[2];
            {
                int r = w * 16 + (lane & 15);
                int base = r * 128, sw = (r & 7) << 4;
                pf[0] = *(const bf16x8*)((char*)QP + base + ((((lane >> 4) * 16) + 0) ^ sw));
                pf[1] = *(const bf16x8*)((char*)QP + base + ((((lane >> 4) * 16) + 64) ^ sw));
            }
#pragma unroll
            for (int nt = 0; nt < 4; ++nt) {
                int d = nt * 16 + (lane & 15);
                int base = d * 128, sw = (d & 7) << 4;
                bf16x8 v0 = *(const bf16x8*)(Vc + base + ((((lane >> 4) * 16) + 0) ^ sw));
                bf16x8 v1 = *(const bf16x8*)(Vc + base + ((((lane >> 4) * 16) + 64) ^ sw));
                acc[nt] = __builtin_amdgcn_mfma_f32_16x16x32_bf16(pf[0], v0, acc[nt], 0, 0, 0);
                acc[nt] = __builtin_amdgcn_mfma_f32_16x16x32_bf16(pf[1], v1, acc[nt], 0, 0, 0);
            }
            cur ^= 1;
        }

#pragma unroll
        for (int i = 0; i < 4; ++i) {
            float inv = 1.0f / lrow[i];
            int q = q0 + w * 16 + (lane >> 4) * 4 + i;
#pragma unroll
            for (int nt = 0; nt < 4; ++nt) {
                int col = h * 64 + nt * 16 + (lane & 15);
                Ob[(size_t)(q * 2 + b) * HID + col] = f2bf(acc[nt][i] * inv);
            }
        }
    }
}

// ---------------------------------------------------------------------------
// Workspace (48 MB): hs_bf 8 | Wqkv_bf 6 | Wo_bf 2 | Q_bf 8 | K_bf 8 |
// Vt_bf 8 | ctx_bf 8
// ---------------------------------------------------------------------------
extern "C" void kernel_launch(void* const* d_in, const int* in_sizes, int n_in,
                              void* d_out, int out_size, void* d_ws, size_t ws_size,
                              hipStream_t stream) {
    const float* hs = (const float*)d_in[0];
    const float* Wq = (const float*)d_in[2];
    const float* bq = (const float*)d_in[3];
    const float* Wk = (const float*)d_in[4];
    const float* bk = (const float*)d_in[5];
    const float* Wv = (const float*)d_in[6];
    const float* bv = (const float*)d_in[7];
    const float* Wo = (const float*)d_in[8];
    const float* bo = (const float*)d_in[9];

    char* ws = (char*)d_ws;
    unsigned short* hs_bf   = (unsigned short*)(ws);
    unsigned short* Wqkv_bf = (unsigned short*)(ws + (8u << 20));   // 3072x1024
    unsigned short* Wo_bf   = (unsigned short*)(ws + (14u << 20));
    unsigned short* Q_bf    = (unsigned short*)(ws + (16u << 20));
    unsigned short* K_bf    = (unsigned short*)(ws + (24u << 20));
    unsigned short* Vt_bf   = (unsigned short*)(ws + (32u << 20));
    unsigned short* ctx_bf  = (unsigned short*)(ws + (40u << 20));

    dim3 blk(256);
    const int WN8 = HID * HID / 8;
    hipLaunchKernelGGL(f2bf_kern, dim3(MROWS * HID / 8 / 256), blk, 0, stream, hs, hs_bf, MROWS * HID / 8);
    hipLaunchKernelGGL(f2bf_kern, dim3(WN8 / 256), blk, 0, stream, Wq, Wqkv_bf, WN8);
    hipLaunchKernelGGL(f2bf_kern, dim3(WN8 / 256), blk, 0, stream, Wk, Wqkv_bf + (size_t)HID * HID, WN8);
    hipLaunchKernelGGL(f2bf_kern, dim3(WN8 / 256), blk, 0, stream, Wv, Wqkv_bf + (size_t)2 * HID * HID, WN8);
    hipLaunchKernelGGL(f2bf_kern, dim3(WN8 / 256), blk, 0, stream, Wo, Wo_bf, WN8);

    // fused QKV projection: N=3072, grid (64,24) = 1536 blocks (6/CU)
    hipLaunchKernelGGL(gemm_bf16, dim3(MROWS / 64, 24), blk, 0, stream,
                       hs_bf, Wqkv_bf, bq, bk, bv, Q_bf, K_bf, Vt_bf, (float*)nullptr, 0);

    hipLaunchKernelGGL(attn_mfma, dim3(16, 32), blk, 0, stream,
                       Q_bf, K_bf, Vt_bf, ctx_bf);

    // output projection: N=1024, grid (64,8) = 512 blocks (2/CU)
    hipLaunchKernelGGL(gemm_bf16, dim3(MROWS / 64, 8), blk, 0, stream,
                       ctx_bf, Wo_bf, bo, bo, bo,
                       (unsigned short*)nullptr, (unsigned short*)nullptr,
                       (unsigned short*)nullptr, (float*)d_out, 1);
}